// Round 1
// baseline (142.129 us; speedup 1.0000x reference)
//
#include <hip/hip_runtime.h>
#include <math.h>

#define D 16
#define K 16
#define BLK 256
#define MPT 4   // points per thread: amortizes LDS broadcast reads over 4 FMAs

// ---------------------------------------------------------------------------
// Prep kernel: per cluster k (one block, one wave):
//   L = chol(Sigma_k)  (lower)
//   U = L^-1           (lower triangular)
//   U' = U / sqrt(2)   (folds the 0.5 of the Mahalanobis term)
//   t' = U' * mu_k
//   c_k = log(pi_k) - sum(log(diag(L)))
// ---------------------------------------------------------------------------
__global__ __launch_bounds__(64) void gmm_prep(
    const float* __restrict__ pi, const float* __restrict__ mu,
    const float* __restrict__ Sigma, float* __restrict__ Uo,
    float* __restrict__ To, float* __restrict__ Co)
{
    const int k = blockIdx.x;
    const int lane = threadIdx.x;  // 0..63, use 0..15 for math
    __shared__ float Lm[D][D];
    __shared__ float Um[D][D];
    __shared__ float colbuf[D];

    for (int t = lane; t < D * D; t += 64)
        (&Lm[0][0])[t] = Sigma[k * D * D + t];
    __syncthreads();

    // In-place Cholesky, column by column; lanes j..15 handle column j rows.
    for (int j = 0; j < D; ++j) {
        float tmp = 0.f;
        if (lane >= j && lane < D) {
            tmp = Lm[lane][j];
            for (int p = 0; p < j; ++p) tmp -= Lm[lane][p] * Lm[j][p];
            colbuf[lane] = tmp;
        }
        __syncthreads();
        float ljj = sqrtf(colbuf[j]);
        if (lane >= j && lane < D)
            Lm[lane][j] = (lane == j) ? ljj : tmp / ljj;
        __syncthreads();
    }

    // Invert lower-triangular L: lane j computes column j of U.
    if (lane < D) {
        const int j = lane;
        for (int i = 0; i < D; ++i) Um[i][j] = 0.f;
        Um[j][j] = 1.f / Lm[j][j];
        for (int i = j + 1; i < D; ++i) {
            float s = 0.f;
            for (int p = j; p < i; ++p) s += Lm[i][p] * Um[p][j];
            Um[i][j] = -s / Lm[i][i];
        }
    }
    __syncthreads();

    const float invs2 = 0.70710678118654752440f;
    for (int t = lane; t < D * D; t += 64)
        Uo[k * D * D + t] = (&Um[0][0])[t] * invs2;

    if (lane < D) {
        float acc = 0.f;
        for (int j = 0; j <= lane; ++j) acc += Um[lane][j] * mu[k * D + j];
        To[k * D + lane] = acc * invs2;
    }
    if (lane == 0) {
        float hl = 0.f;
        for (int i = 0; i < D; ++i) hl += logf(Lm[i][i]);
        Co[k] = logf(pi[k]) - hl;
    }
}

// ---------------------------------------------------------------------------
// Main kernel: each thread owns MPT points.
//   s_k = c_k - || U' x - t' ||^2 ; out = softmax_k(s_k)
// U'/t'/c live in LDS; all reads are wave-uniform (broadcast, conflict-free),
// amortized over MPT points per load.
// ---------------------------------------------------------------------------
__global__ __launch_bounds__(BLK) void gmm_main(
    const float* __restrict__ x, const float* __restrict__ Uall,
    const float* __restrict__ Tall, const float* __restrict__ Call,
    float* __restrict__ out, int N)
{
    __shared__ float sU[K][D][D];   // 16 KB
    __shared__ float sT[K][D];
    __shared__ float sC[K];

    const int tid = threadIdx.x;
    for (int t = tid; t < K * D * D; t += BLK) (&sU[0][0][0])[t] = Uall[t];
    for (int t = tid; t < K * D; t += BLK)     (&sT[0][0])[t]    = Tall[t];
    if (tid < K) sC[tid] = Call[tid];
    __syncthreads();

    const long long base = (long long)blockIdx.x * (BLK * MPT) + tid;

    float xv[MPT][D];
    int   nidx[MPT];
    bool  ok[MPT];
#pragma unroll
    for (int m = 0; m < MPT; ++m) {
        long long n = base + (long long)m * BLK;
        nidx[m] = (int)n;
        ok[m] = (n < (long long)N);
        if (ok[m]) {
            const float4* p = (const float4*)(x + n * D);
            float4 a = p[0], b = p[1], c = p[2], d4 = p[3];
            xv[m][0] = a.x;  xv[m][1] = a.y;  xv[m][2] = a.z;  xv[m][3] = a.w;
            xv[m][4] = b.x;  xv[m][5] = b.y;  xv[m][6] = b.z;  xv[m][7] = b.w;
            xv[m][8] = c.x;  xv[m][9] = c.y;  xv[m][10] = c.z; xv[m][11] = c.w;
            xv[m][12] = d4.x; xv[m][13] = d4.y; xv[m][14] = d4.z; xv[m][15] = d4.w;
        } else {
#pragma unroll
            for (int j = 0; j < D; ++j) xv[m][j] = 0.f;
        }
    }

    float res[MPT][K];
#pragma unroll 1               // keep the k-loop rolled: body ~fits I-cache
    for (int k = 0; k < K; ++k) {
        float acc[MPT];
#pragma unroll
        for (int m = 0; m < MPT; ++m) acc[m] = 0.f;
#pragma unroll
        for (int i = 0; i < D; ++i) {
            float y[MPT];
            float tv = sT[k][i];
#pragma unroll
            for (int m = 0; m < MPT; ++m) y[m] = -tv;
#pragma unroll
            for (int j = 0; j <= i; ++j) {
                float u = sU[k][i][j];
#pragma unroll
                for (int m = 0; m < MPT; ++m) y[m] = fmaf(u, xv[m][j], y[m]);
            }
#pragma unroll
            for (int m = 0; m < MPT; ++m) acc[m] = fmaf(y[m], y[m], acc[m]);
        }
        float ck = sC[k];
#pragma unroll
        for (int m = 0; m < MPT; ++m) res[m][k] = ck - acc[m];
    }

#pragma unroll
    for (int m = 0; m < MPT; ++m) {
        if (!ok[m]) continue;
        float mx = res[m][0];
#pragma unroll
        for (int k2 = 1; k2 < K; ++k2) mx = fmaxf(mx, res[m][k2]);
        float sum = 0.f;
#pragma unroll
        for (int k2 = 0; k2 < K; ++k2) {
            float e = __expf(res[m][k2] - mx);
            res[m][k2] = e;
            sum += e;
        }
        float inv = 1.f / sum;
        float4* po = (float4*)(out + (long long)nidx[m] * K);
        float4 o;
        o.x = res[m][0] * inv;  o.y = res[m][1] * inv;
        o.z = res[m][2] * inv;  o.w = res[m][3] * inv;   po[0] = o;
        o.x = res[m][4] * inv;  o.y = res[m][5] * inv;
        o.z = res[m][6] * inv;  o.w = res[m][7] * inv;   po[1] = o;
        o.x = res[m][8] * inv;  o.y = res[m][9] * inv;
        o.z = res[m][10] * inv; o.w = res[m][11] * inv;  po[2] = o;
        o.x = res[m][12] * inv; o.y = res[m][13] * inv;
        o.z = res[m][14] * inv; o.w = res[m][15] * inv;  po[3] = o;
    }
}

extern "C" void kernel_launch(void* const* d_in, const int* in_sizes, int n_in,
                              void* d_out, int out_size, void* d_ws, size_t ws_size,
                              hipStream_t stream) {
    const float* x     = (const float*)d_in[0];   // (N, D)
    const float* pi    = (const float*)d_in[1];   // (1, K)
    const float* mu    = (const float*)d_in[2];   // (K, 1, D)
    const float* Sigma = (const float*)d_in[3];   // (K, D, D)
    float* out = (float*)d_out;                   // (N, K)
    const int N = in_sizes[0] / D;

    float* Uo = (float*)d_ws;            // K*D*D floats
    float* To = Uo + K * D * D;          // K*D floats
    float* Co = To + K * D;              // K floats

    gmm_prep<<<K, 64, 0, stream>>>(pi, mu, Sigma, Uo, To, Co);

    const int pts_per_blk = BLK * MPT;
    const int grid = (N + pts_per_blk - 1) / pts_per_blk;
    gmm_main<<<grid, BLK, 0, stream>>>(x, Uo, To, Co, out, N);
}

// Round 2
// 128.709 us; speedup vs baseline: 1.1043x; 1.1043x over previous
//
#include <hip/hip_runtime.h>
#include <math.h>

#define D 16
#define K 16
#define BLK 64
#define MPT 2
#define PSTRIDE 176   // per-cluster param stride in floats (704 B, 64B-aligned)

__host__ __device__ constexpr int tri(int i, int j) { return i * (i + 1) / 2 + j; }

// ---------------------------------------------------------------------------
// Prep: one wave; lane k handles cluster k entirely in registers.
//   packed lower-tri M <- Sigma_k ; chol in place ; invert in place ;
//   P[k] = { c_k, T' = U'mu, U' = L^-1/sqrt(2) }
// Fully unrolled so M[] stays in VGPRs (~160), dependent chain ~1600 VALU ops
// => ~3 us for all 16 clusters.
// ---------------------------------------------------------------------------
__global__ __launch_bounds__(64) void gmm_prep(
    const float* __restrict__ pi, const float* __restrict__ mu,
    const float* __restrict__ Sigma, float* __restrict__ P)
{
    const int k = threadIdx.x;
    if (k >= K) return;

    float M[tri(D - 1, D - 1) + 1];   // 136 packed lower-tri

#pragma unroll
    for (int i = 0; i < D; ++i)
#pragma unroll
        for (int j = 0; j <= i; ++j)
            M[tri(i, j)] = Sigma[k * D * D + i * D + j];

    // Cholesky, packed, in place.
    float hl = 0.f;
#pragma unroll
    for (int j = 0; j < D; ++j) {
        float s = M[tri(j, j)];
#pragma unroll
        for (int p = 0; p < j; ++p) s -= M[tri(j, p)] * M[tri(j, p)];
        float ljj = sqrtf(s);
        M[tri(j, j)] = ljj;
        hl += logf(ljj);
        float inv = 1.f / ljj;
#pragma unroll
        for (int i = j + 1; i < D; ++i) {
            float t = M[tri(i, j)];
#pragma unroll
            for (int p = 0; p < j; ++p) t -= M[tri(i, p)] * M[tri(j, p)];
            M[tri(i, j)] = t * inv;
        }
    }

    // Invert lower-triangular in place: column j ascending; reads of
    // L[i][p] (p>j) and L[i][i] are original, U[p][j] already written.
#pragma unroll
    for (int j = 0; j < D; ++j) {
        float ujj = 1.f / M[tri(j, j)];
        M[tri(j, j)] = ujj;
#pragma unroll
        for (int i = j + 1; i < D; ++i) {
            float s = 0.f;
#pragma unroll
            for (int p = j; p < i; ++p) s += M[tri(i, p)] * M[tri(p, j)];
            M[tri(i, j)] = -s / M[tri(i, i)];
        }
    }

    const float invs2 = 0.70710678118654752440f;
    float* Pk = P + k * PSTRIDE;
    Pk[0] = logf(pi[k]) - hl;
    // T' = U' * mu  (U row i needs mu[0..i])
#pragma unroll
    for (int i = 0; i < D; ++i) {
        float acc = 0.f;
#pragma unroll
        for (int j = 0; j <= i; ++j) acc += M[tri(i, j)] * mu[k * D + j];
        Pk[16 + i] = acc * invs2;
    }
#pragma unroll
    for (int t = 0; t < tri(D - 1, D - 1) + 1; ++t)
        Pk[32 + t] = M[t] * invs2;
}

// ---------------------------------------------------------------------------
// Main: thread owns MPT points. Params read via wave-uniform addresses ->
// s_load on the SMEM pipe (no LDS at all; frees LDS + keeps VALU fed).
//   s_k = c_k - ||U'x - T'||^2 ; out = softmax_k(s_k)
// ---------------------------------------------------------------------------
__global__ __launch_bounds__(BLK) void gmm_main(
    const float* __restrict__ x, const float* __restrict__ P,
    float* __restrict__ out, int N)
{
    const int tid = threadIdx.x;
    const long long base = (long long)blockIdx.x * (BLK * MPT) + tid;

    float xv[MPT][D];
    int   nidx[MPT];
    bool  ok[MPT];
#pragma unroll
    for (int m = 0; m < MPT; ++m) {
        long long n = base + (long long)m * BLK;
        nidx[m] = (int)n;
        ok[m] = (n < (long long)N);
        if (ok[m]) {
            const float4* p = (const float4*)(x + n * D);
            float4 a = p[0], b = p[1], c = p[2], d4 = p[3];
            xv[m][0] = a.x;  xv[m][1] = a.y;  xv[m][2] = a.z;  xv[m][3] = a.w;
            xv[m][4] = b.x;  xv[m][5] = b.y;  xv[m][6] = b.z;  xv[m][7] = b.w;
            xv[m][8] = c.x;  xv[m][9] = c.y;  xv[m][10] = c.z; xv[m][11] = c.w;
            xv[m][12] = d4.x; xv[m][13] = d4.y; xv[m][14] = d4.z; xv[m][15] = d4.w;
        } else {
#pragma unroll
            for (int j = 0; j < D; ++j) xv[m][j] = 0.f;
        }
    }

    float res[MPT][K];
#pragma unroll 1            // keep k rolled: ~350-instr body, s_loads per iter
    for (int k = 0; k < K; ++k) {
        const float* __restrict__ Pk = P + k * PSTRIDE;   // uniform address
        float acc[MPT];
#pragma unroll
        for (int m = 0; m < MPT; ++m) acc[m] = 0.f;
#pragma unroll
        for (int i = 0; i < D; ++i) {
            float tv = Pk[16 + i];
            float y[MPT];
#pragma unroll
            for (int m = 0; m < MPT; ++m) y[m] = -tv;
#pragma unroll
            for (int j = 0; j <= i; ++j) {
                float u = Pk[32 + tri(i, j)];
#pragma unroll
                for (int m = 0; m < MPT; ++m) y[m] = fmaf(u, xv[m][j], y[m]);
            }
#pragma unroll
            for (int m = 0; m < MPT; ++m) acc[m] = fmaf(y[m], y[m], acc[m]);
        }
        float ck = Pk[0];
#pragma unroll
        for (int m = 0; m < MPT; ++m) res[m][k] = ck - acc[m];
    }

#pragma unroll
    for (int m = 0; m < MPT; ++m) {
        if (!ok[m]) continue;
        float mx = res[m][0];
#pragma unroll
        for (int k2 = 1; k2 < K; ++k2) mx = fmaxf(mx, res[m][k2]);
        float sum = 0.f;
#pragma unroll
        for (int k2 = 0; k2 < K; ++k2) {
            float e = __expf(res[m][k2] - mx);
            res[m][k2] = e;
            sum += e;
        }
        float inv = 1.f / sum;
        float4* po = (float4*)(out + (long long)nidx[m] * K);
        float4 o;
        o.x = res[m][0] * inv;  o.y = res[m][1] * inv;
        o.z = res[m][2] * inv;  o.w = res[m][3] * inv;   po[0] = o;
        o.x = res[m][4] * inv;  o.y = res[m][5] * inv;
        o.z = res[m][6] * inv;  o.w = res[m][7] * inv;   po[1] = o;
        o.x = res[m][8] * inv;  o.y = res[m][9] * inv;
        o.z = res[m][10] * inv; o.w = res[m][11] * inv;  po[2] = o;
        o.x = res[m][12] * inv; o.y = res[m][13] * inv;
        o.z = res[m][14] * inv; o.w = res[m][15] * inv;  po[3] = o;
    }
}

extern "C" void kernel_launch(void* const* d_in, const int* in_sizes, int n_in,
                              void* d_out, int out_size, void* d_ws, size_t ws_size,
                              hipStream_t stream) {
    const float* x     = (const float*)d_in[0];   // (N, D)
    const float* pi    = (const float*)d_in[1];   // (1, K)
    const float* mu    = (const float*)d_in[2];   // (K, 1, D)
    const float* Sigma = (const float*)d_in[3];   // (K, D, D)
    float* out = (float*)d_out;                   // (N, K)
    const int N = in_sizes[0] / D;

    float* P = (float*)d_ws;                      // K * PSTRIDE floats

    gmm_prep<<<1, 64, 0, stream>>>(pi, mu, Sigma, P);

    const int pts_per_blk = BLK * MPT;
    const int grid = (N + pts_per_blk - 1) / pts_per_blk;
    gmm_main<<<grid, BLK, 0, stream>>>(x, P, out, N);
}

// Round 3
// 124.215 us; speedup vs baseline: 1.1442x; 1.0362x over previous
//
#include <hip/hip_runtime.h>
#include <math.h>

#define D 16
#define K 16
#define BLK 256
#define MPT 2          // 2 points per thread, packed as float2 -> v_pk_fma_f32
#define PSTRIDE 176    // per-cluster param stride in floats (704 B)

typedef float v2 __attribute__((ext_vector_type(2)));

__host__ __device__ constexpr int tri(int i, int j) { return i * (i + 1) / 2 + j; }

static __device__ __forceinline__ v2 fma2(v2 a, v2 b, v2 c) {
#if __has_builtin(__builtin_elementwise_fma)
    return __builtin_elementwise_fma(a, b, c);
#else
    v2 r; r.x = fmaf(a.x, b.x, c.x); r.y = fmaf(a.y, b.y, c.y); return r;
#endif
}
static __device__ __forceinline__ v2 max2(v2 a, v2 b) {
#if __has_builtin(__builtin_elementwise_max)
    return __builtin_elementwise_max(a, b);
#else
    v2 r; r.x = fmaxf(a.x, b.x); r.y = fmaxf(a.y, b.y); return r;
#endif
}

// ---------------------------------------------------------------------------
// Prep: one wave; lane k handles cluster k entirely in registers (~2 us).
//   P[k] = { c_k, T' = U'mu, U' = chol(Sigma)^-1 / sqrt(2) }
// ---------------------------------------------------------------------------
__global__ __launch_bounds__(64) void gmm_prep(
    const float* __restrict__ pi, const float* __restrict__ mu,
    const float* __restrict__ Sigma, float* __restrict__ P)
{
    const int k = threadIdx.x;
    if (k >= K) return;

    float M[tri(D - 1, D - 1) + 1];   // 136 packed lower-tri

#pragma unroll
    for (int i = 0; i < D; ++i)
#pragma unroll
        for (int j = 0; j <= i; ++j)
            M[tri(i, j)] = Sigma[k * D * D + i * D + j];

    // Cholesky, packed, in place.
    float hl = 0.f;
#pragma unroll
    for (int j = 0; j < D; ++j) {
        float s = M[tri(j, j)];
#pragma unroll
        for (int p = 0; p < j; ++p) s -= M[tri(j, p)] * M[tri(j, p)];
        float ljj = sqrtf(s);
        M[tri(j, j)] = ljj;
        hl += logf(ljj);
        float inv = 1.f / ljj;
#pragma unroll
        for (int i = j + 1; i < D; ++i) {
            float t = M[tri(i, j)];
#pragma unroll
            for (int p = 0; p < j; ++p) t -= M[tri(i, p)] * M[tri(j, p)];
            M[tri(i, j)] = t * inv;
        }
    }

    // Invert lower-triangular in place (column j ascending).
#pragma unroll
    for (int j = 0; j < D; ++j) {
        float ujj = 1.f / M[tri(j, j)];
        M[tri(j, j)] = ujj;
#pragma unroll
        for (int i = j + 1; i < D; ++i) {
            float s = 0.f;
#pragma unroll
            for (int p = j; p < i; ++p) s += M[tri(i, p)] * M[tri(p, j)];
            M[tri(i, j)] = -s / M[tri(i, i)];
        }
    }

    const float invs2 = 0.70710678118654752440f;
    float* Pk = P + k * PSTRIDE;
    Pk[0] = logf(pi[k]) - hl;
#pragma unroll
    for (int i = 0; i < D; ++i) {
        float acc = 0.f;
#pragma unroll
        for (int j = 0; j <= i; ++j) acc += M[tri(i, j)] * mu[k * D + j];
        Pk[16 + i] = acc * invs2;
    }
#pragma unroll
    for (int t = 0; t < tri(D - 1, D - 1) + 1; ++t)
        Pk[32 + t] = M[t] * invs2;
}

// ---------------------------------------------------------------------------
// Main: each thread owns 2 points, carried as a packed float2 stream so the
// triangular product issues as v_pk_fma_f32 (2 FMA/instr). Params arrive via
// wave-uniform s_load batches on the SMEM pipe (no LDS, no VALU addr math).
//   s_k = c_k - ||U'x - T'||^2 ; out = softmax_k(s_k)
// ---------------------------------------------------------------------------
__global__ __launch_bounds__(BLK) void gmm_main(
    const float* __restrict__ x, const float* __restrict__ P,
    float* __restrict__ out, int N)
{
    const int tid = threadIdx.x;
    const long long n0 = (long long)blockIdx.x * (BLK * MPT) + tid;
    const long long n1 = n0 + BLK;
    const bool ok0 = n0 < (long long)N;
    const bool ok1 = n1 < (long long)N;

    // xv2[j] = { x[n0][j], x[n1][j] } — packed across the two points.
    v2 xv2[D];
    {
        float4 a0 = {0,0,0,0}, b0 = a0, c0 = a0, d0 = a0;
        float4 a1 = a0, b1 = a0, c1 = a0, d1 = a0;
        if (ok0) {
            const float4* p = (const float4*)(x + n0 * D);
            a0 = p[0]; b0 = p[1]; c0 = p[2]; d0 = p[3];
        }
        if (ok1) {
            const float4* p = (const float4*)(x + n1 * D);
            a1 = p[0]; b1 = p[1]; c1 = p[2]; d1 = p[3];
        }
        xv2[0]  = (v2){a0.x, a1.x}; xv2[1]  = (v2){a0.y, a1.y};
        xv2[2]  = (v2){a0.z, a1.z}; xv2[3]  = (v2){a0.w, a1.w};
        xv2[4]  = (v2){b0.x, b1.x}; xv2[5]  = (v2){b0.y, b1.y};
        xv2[6]  = (v2){b0.z, b1.z}; xv2[7]  = (v2){b0.w, b1.w};
        xv2[8]  = (v2){c0.x, c1.x}; xv2[9]  = (v2){c0.y, c1.y};
        xv2[10] = (v2){c0.z, c1.z}; xv2[11] = (v2){c0.w, c1.w};
        xv2[12] = (v2){d0.x, d1.x}; xv2[13] = (v2){d0.y, d1.y};
        xv2[14] = (v2){d0.z, d1.z}; xv2[15] = (v2){d0.w, d1.w};
    }

    v2 res2[K];
#pragma unroll 1            // keep k rolled; per-k SMEM batch + ~190 VALU
    for (int k = 0; k < K; ++k) {
        const float* __restrict__ Pk = P + k * PSTRIDE;   // uniform address
        v2 acc = (v2){0.f, 0.f};
#pragma unroll
        for (int i = 0; i < D; ++i) {
            float tv = Pk[16 + i];
            v2 y = (v2){-tv, -tv};
#pragma unroll
            for (int j = 0; j <= i; ++j) {
                float u = Pk[32 + tri(i, j)];
                y = fma2((v2){u, u}, xv2[j], y);
            }
            acc = fma2(y, y, acc);
        }
        float ck = Pk[0];
        res2[k] = (v2){ck, ck} - acc;
    }

    // Packed softmax over k for both points.
    v2 mx = res2[0];
#pragma unroll
    for (int k = 1; k < K; ++k) mx = max2(mx, res2[k]);
    v2 sum = (v2){0.f, 0.f};
#pragma unroll
    for (int k = 0; k < K; ++k) {
        v2 d = res2[k] - mx;
        v2 e; e.x = __expf(d.x); e.y = __expf(d.y);
        res2[k] = e;
        sum = sum + e;
    }
    float inv0 = 1.f / sum.x;
    float inv1 = 1.f / sum.y;

    if (ok0) {
        float4* po = (float4*)(out + n0 * D);
        po[0] = (float4){res2[0].x * inv0,  res2[1].x * inv0,
                         res2[2].x * inv0,  res2[3].x * inv0};
        po[1] = (float4){res2[4].x * inv0,  res2[5].x * inv0,
                         res2[6].x * inv0,  res2[7].x * inv0};
        po[2] = (float4){res2[8].x * inv0,  res2[9].x * inv0,
                         res2[10].x * inv0, res2[11].x * inv0};
        po[3] = (float4){res2[12].x * inv0, res2[13].x * inv0,
                         res2[14].x * inv0, res2[15].x * inv0};
    }
    if (ok1) {
        float4* po = (float4*)(out + n1 * D);
        po[0] = (float4){res2[0].y * inv1,  res2[1].y * inv1,
                         res2[2].y * inv1,  res2[3].y * inv1};
        po[1] = (float4){res2[4].y * inv1,  res2[5].y * inv1,
                         res2[6].y * inv1,  res2[7].y * inv1};
        po[2] = (float4){res2[8].y * inv1,  res2[9].y * inv1,
                         res2[10].y * inv1, res2[11].y * inv1};
        po[3] = (float4){res2[12].y * inv1, res2[13].y * inv1,
                         res2[14].y * inv1, res2[15].y * inv1};
    }
}

extern "C" void kernel_launch(void* const* d_in, const int* in_sizes, int n_in,
                              void* d_out, int out_size, void* d_ws, size_t ws_size,
                              hipStream_t stream) {
    const float* x     = (const float*)d_in[0];   // (N, D)
    const float* pi    = (const float*)d_in[1];   // (1, K)
    const float* mu    = (const float*)d_in[2];   // (K, 1, D)
    const float* Sigma = (const float*)d_in[3];   // (K, D, D)
    float* out = (float*)d_out;                   // (N, K)
    const int N = in_sizes[0] / D;

    float* P = (float*)d_ws;                      // K * PSTRIDE floats

    gmm_prep<<<1, 64, 0, stream>>>(pi, mu, Sigma, P);

    const int pts_per_blk = BLK * MPT;
    const int grid = (N + pts_per_blk - 1) / pts_per_blk;
    gmm_main<<<grid, BLK, 0, stream>>>(x, P, out, N);
}